// Round 4
// baseline (95.415 us; speedup 1.0000x reference)
//
#include <hip/hip_runtime.h>
#include <math.h>

#define NB  2048
#define PT  1024          // prep threads (1 block)
#define EPT 16            // elements per prep thread (n = 16384)
#define BLK 256

// ws layout (bytes):
//   0     : int    offsets[NB]   (8192)
//   8192  : int    cntArr[NB]    (8192)
//   16384 : float  suffixGT[NB]  (8192)
//   24576 : float  wsum
//   24580 : int    done
//   24832 : float2 sorted[N]     (131072)

__device__ __forceinline__ int bucket_of(float d) {
    int b = (int)(d * (float)NB);   // exact pow2 scale -> exactly monotone
    return min(max(b, 0), NB - 1);
}

__global__ __launch_bounds__(PT)
void prep_kernel(const float* __restrict__ hazard,
                 const float* __restrict__ durations,
                 int* __restrict__ offsets, int* __restrict__ cntArr,
                 float* __restrict__ suffixGT,
                 float* __restrict__ wsum, int* __restrict__ done,
                 float2* __restrict__ sorted, int n) {
    __shared__ float histF[NB];
    __shared__ int   histC[NB];
    __shared__ int   curL[NB];
    __shared__ float wtF[16];
    __shared__ int   wtC[16];
    const int tid  = threadIdx.x;
    const int lane = tid & 63;
    const int wv   = tid >> 6;

    // phase 0: zero LDS hist
    histF[tid] = 0.0f; histF[tid + PT] = 0.0f;
    histC[tid] = 0;    histC[tid + PT] = 0;
    __syncthreads();

    // phase 1: build histogram, keep (d,e) in registers
    float dv[EPT], ev[EPT];
    #pragma unroll
    for (int k = 0; k < EPT; ++k) {
        int i = tid + k * PT;                 // coalesced
        dv[k] = durations[i];
        ev[k] = expf(hazard[i]);
        int b = bucket_of(dv[k]);
        atomicAdd(&histF[b], ev[k]);          // LDS float atomic
        atomicAdd(&histC[b], 1);
    }
    __syncthreads();

    // phase 2: dual scan — cnt forward, sumExp reversed (for suffix sums)
    int   c0 = histC[2 * tid], c1 = histC[2 * tid + 1];
    float f0 = histF[NB - 1 - 2 * tid];       // k = 2t   (reversed)
    float f1 = histF[NB - 2 - 2 * tid];       // k = 2t+1
    int   cp = c0 + c1;
    float fp = f0 + f1;
    #pragma unroll
    for (int o = 1; o < 64; o <<= 1) {        // wave-inclusive scan of pair-sums
        int   cu = __shfl_up(cp, o, 64);
        float fu = __shfl_up(fp, o, 64);
        if (lane >= o) { cp += cu; fp += fu; }
    }
    if (lane == 63) { wtC[wv] = cp; wtF[wv] = fp; }
    __syncthreads();
    if (wv == 0) {                            // scan the 16 wave totals
        int   c = (lane < 16) ? wtC[lane] : 0;
        float f = (lane < 16) ? wtF[lane] : 0.0f;
        #pragma unroll
        for (int o = 1; o < 16; o <<= 1) {
            int   cu = __shfl_up(c, o, 64);
            float fu = __shfl_up(f, o, 64);
            if (lane >= o) { c += cu; f += fu; }
        }
        if (lane < 16) { wtC[lane] = c; wtF[lane] = f; }
    }
    __syncthreads();
    int   cbase = (wv > 0) ? wtC[wv - 1] : 0;
    float fbase = (wv > 0) ? wtF[wv - 1] : 0.0f;
    int   cI1 = cbase + cp;                   // inclusive cnt-scan at bucket 2t+1
    int   cI0 = cI1 - c1;                     // at bucket 2t
    float fI1 = fbase + fp;                   // RInc at k=2t+1
    float fI0 = fI1 - f1;                     // RInc at k=2t

    int b0 = 2 * tid, b1 = 2 * tid + 1;
    int e0 = cI0 - c0, e1 = cI1 - c1;         // exclusive offsets
    offsets[b0] = e0;  offsets[b1] = e1;
    curL[b0]    = e0;  curL[b1]    = e1;
    cntArr[b0]  = c0;  cntArr[b1]  = c1;
    // suffixGT[b] = RInc[NB-2-b]:  k=2t -> b = NB-2-2t ;  k=2t+1 -> b = NB-3-2t
    suffixGT[NB - 2 - 2 * tid] = fI0;
    {
        int bb = NB - 3 - 2 * tid;
        if (bb >= 0) suffixGT[bb] = fI1;
    }
    if (tid == 0) { suffixGT[NB - 1] = 0.0f; wsum[0] = 0.0f; done[0] = 0; }
    __syncthreads();

    // phase 3: bucket-sort scatter straight from registers via LDS cursors
    #pragma unroll
    for (int k = 0; k < EPT; ++k) {
        int b = bucket_of(dv[k]);
        int pos = atomicAdd(&curL[b], 1);
        sorted[pos] = make_float2(dv[k], ev[k]);
    }
}

__global__ __launch_bounds__(BLK)
void loss_kernel(const float* __restrict__ hazard,
                 const float* __restrict__ durations,
                 const float* __restrict__ events,
                 const int* __restrict__ offsets, const int* __restrict__ cntArr,
                 const float* __restrict__ suffixGT,
                 const float2* __restrict__ sorted,
                 float* __restrict__ wsum, int* __restrict__ done,
                 float* __restrict__ out, int n) {
    const int i = blockIdx.x * BLK + threadIdx.x;   // grid covers n exactly
    float d = durations[i];
    int b = bucket_of(d);
    float s = suffixGT[b];
    int off = offsets[b], c = cntArr[b];
    for (int k = 0; k < c; ++k) {                   // avg 8, max ~30
        float2 v = sorted[off + k];
        s += (v.x >= d) ? v.y : 0.0f;               // includes j==i -> s > 0
    }
    float local = (hazard[i] - logf(s)) * events[i];

    #pragma unroll
    for (int o = 32; o > 0; o >>= 1)
        local += __shfl_down(local, o, 64);

    __shared__ float wpart[BLK / 64];
    if ((threadIdx.x & 63) == 0) wpart[threadIdx.x >> 6] = local;
    __syncthreads();
    if (threadIdx.x == 0) {
        float t = 0.0f;
        #pragma unroll
        for (int w = 0; w < BLK / 64; ++w) t += wpart[w];
        atomicAdd(wsum, t);
        __threadfence();
        int ticket = atomicAdd(done, 1);
        if (ticket == (int)gridDim.x - 1) {
            float tot = atomicAdd(wsum, 0.0f);      // atomic read: all adds visible
            out[0] = -tot / (float)n;
        }
    }
}

extern "C" void kernel_launch(void* const* d_in, const int* in_sizes, int n_in,
                              void* d_out, int out_size, void* d_ws, size_t ws_size,
                              hipStream_t stream) {
    const float* hazard    = (const float*)d_in[0];
    const float* durations = (const float*)d_in[1];
    const float* events    = (const float*)d_in[2];
    float* out = (float*)d_out;
    const int n = in_sizes[1];

    char* ws = (char*)d_ws;
    int*    offsets  = (int*)  (ws + 0);
    int*    cntArr   = (int*)  (ws + 8192);
    float*  suffixGT = (float*)(ws + 16384);
    float*  wsum     = (float*)(ws + 24576);
    int*    done     = (int*)  (ws + 24580);
    float2* sorted   = (float2*)(ws + 24832);

    prep_kernel<<<1, PT, 0, stream>>>(hazard, durations, offsets, cntArr,
                                      suffixGT, wsum, done, sorted, n);
    loss_kernel<<<dim3(n / BLK), BLK, 0, stream>>>(hazard, durations, events,
                                                   offsets, cntArr, suffixGT,
                                                   sorted, wsum, done, out, n);
}